// Round 3
// baseline (169.925 us; speedup 1.0000x reference)
//
#include <hip/hip_runtime.h>
#include <math.h>

#define BSZ 128
#define T   512
#define E   128
#define H   128

// Workspace layout (first 1024 bytes zeroed by memset each call):
//   [0]    double accum[2]   {loss_sum, pair_count}
//   [16]   int    done[BSZ]  per-row arrival counters (split-K pattern)
//   [528]  int    scan_done  global scan-completion counter
//   [1024] float  cterm[BSZ*T]
//
// loss = sum_b sum_{m=3}^{len_b-1} [ LSE_{k=m}^{len_b-1} cterm[b,k] - cterm[b,m] ]
//        / sum_b (len_b - 3)
// where cterm[b,k] = dot(enc[b,k,:], fc_w[H:]).  The LSTM hidden term a[b,j]
// and fc_b are separable in (j,k) and cancel exactly between lse and pos.
__global__ __launch_bounds__(512) void dli_fused(
    const float* __restrict__ enc,    // [B,T,E]
    const int*   __restrict__ mask,   // [B,T]
    const float* __restrict__ fc_w,   // [H+E]
    char*        __restrict__ ws,
    float*       __restrict__ out)
{
    double* accum     = (double*)ws;
    int*    done      = (int*)(ws + 16);
    int*    scan_done = (int*)(ws + 528);
    float*  cterm     = (float*)(ws + 1024);

    const int t    = threadIdx.x;
    const int lane = t & 63;
    const int wid  = t >> 6;
    const int b    = blockIdx.x >> 1;
    const int half = blockIdx.x & 1;
    const int hw   = t >> 5;          // half-wave id 0..15
    const int li   = t & 31;          // lane within half-wave

    __shared__ float s_c[T];
    __shared__ float s_e[T];
    __shared__ float s_red[8];
    __shared__ int   s_len;
    __shared__ int   s_flag;

    // ---------- dot phase: this block covers k in [half*256, half*256+256) ----------
    const float4 w4 = *reinterpret_cast<const float4*>(fc_w + H + 4 * li);
    const int kbase = half * 256;
    #pragma unroll 4
    for (int p = 0; p < 16; ++p) {
        const int k = kbase + p * 16 + hw;
        if (mask[b * T + k]) {                 // prefix mask: masked cterm never read
            const float4 v = *reinterpret_cast<const float4*>(
                enc + (size_t)(b * T + k) * E + 4 * li);
            float s = v.x * w4.x + v.y * w4.y + v.z * w4.z + v.w * w4.w;
            #pragma unroll
            for (int off = 16; off >= 1; off >>= 1)
                s += __shfl_xor(s, off);       // xor<=16 stays within half-wave
            if (li == 0) cterm[b * T + k] = s;
        }
    }

    // ---------- release + arrival; second block per row becomes the scanner ----------
    __threadfence();                           // make cterm writes agent-visible
    __syncthreads();
    if (t == 0) {
        s_flag = atomicAdd(&done[b], 1);       // 0 = first, 1 = second (scanner)
        s_len  = 0;
    }
    __syncthreads();
    if (s_flag == 0) return;

    __threadfence();                           // acquire partner's cterm writes

    // ---------- scan phase: suffix-LSE over row b (thread t <-> k=t) ----------
    const int mv = mask[b * T + t];
    unsigned long long bal = __ballot(mv != 0);
    if (lane == 0) atomicAdd(&s_len, __popcll(bal));

    s_c[t] = mv ? cterm[b * T + t] : 0.0f;
    __syncthreads();
    const int len = s_len;

    // row max over k in [3,len)
    float mval = (t >= 3 && t < len) ? s_c[t] : -INFINITY;
    #pragma unroll
    for (int off = 32; off >= 1; off >>= 1)
        mval = fmaxf(mval, __shfl_xor(mval, off));
    if (lane == 0) s_red[wid] = mval;
    __syncthreads();
    if (t == 0) {
        float m = s_red[0];
        #pragma unroll
        for (int i = 1; i < 8; i++) m = fmaxf(m, s_red[i]);
        s_red[0] = m;
    }
    __syncthreads();
    const float Mrow = s_red[0];

    s_e[t] = (t >= 3 && t < len) ? expf(s_c[t] - Mrow) : 0.0f;
    __syncthreads();

    // suffix inclusive sum (Hillis-Steele), 9 steps
    for (int d = 1; d < T; d <<= 1) {
        float add = (t + d < T) ? s_e[t + d] : 0.0f;
        __syncthreads();
        s_e[t] += add;
        __syncthreads();
    }

    float term = 0.0f;
    if (t >= 3 && t < len)
        term = Mrow + logf(s_e[t]) - s_c[t];
    #pragma unroll
    for (int off = 32; off >= 1; off >>= 1)
        term += __shfl_xor(term, off);
    if (lane == 0) s_red[wid] = term;
    __syncthreads();

    if (t == 0) {
        float rs = 0.0f;
        #pragma unroll
        for (int i = 0; i < 8; i++) rs += s_red[i];
        int cnt = len - 3; if (cnt < 0) cnt = 0;
        atomicAdd(&accum[0], (double)rs);
        atomicAdd(&accum[1], (double)cnt);
        __threadfence();
        int old = atomicAdd(scan_done, 1);
        if (old == BSZ - 1) {                  // last scanner finalizes
            double a0 = atomicAdd(&accum[0], 0.0);   // coherent read-back
            double a1 = atomicAdd(&accum[1], 0.0);
            out[0] = (float)(a0 / a1);
        }
    }
}

extern "C" void kernel_launch(void* const* d_in, const int* in_sizes, int n_in,
                              void* d_out, int out_size, void* d_ws, size_t ws_size,
                              hipStream_t stream) {
    const float* enc  = (const float*)d_in[0];   // encoder_output [128,512,128] f32
    const int*   mask = (const int*)d_in[1];     // mask [128,512] i32
    const float* fc_w = (const float*)d_in[6];   // fc_w [1,256] f32
    // d_in[2..5] (LSTM weights) and d_in[7] (fc_b) cancel analytically.

    hipMemsetAsync(d_ws, 0, 1024, stream);       // accum + done[] + scan_done
    dli_fused<<<BSZ * 2, 512, 0, stream>>>(enc, mask, fc_w, (char*)d_ws,
                                           (float*)d_out);
}

// Round 4
// 95.739 us; speedup vs baseline: 1.7749x; 1.7749x over previous
//
#include <hip/hip_runtime.h>
#include <math.h>

#define BSZ 128
#define T   512
#define E   128
#define H   128

// Workspace layout (first 16 bytes + scan_done zeroed by memset each call):
//   [0]   double accum[2]  {loss_sum, pair_count}
//   [16]  int    scan_done
//   [1024] float cterm[B*T]
//
// loss = sum_b sum_{m=3}^{len_b-1} [ LSE_{k=m}^{len_b-1} cterm[b,k] - cterm[b,m] ]
//        / sum_b (len_b - 3)
// where cterm[b,k] = dot(enc[b,k,:], fc_w[H:]).  The LSTM hidden term and fc_b
// are separable in (j,k) and cancel exactly between lse and pos.

// ---------------- Phase 1: cterm = enc . w_e ----------------
// Half-wave (32 lanes x float4) per row; 8 rows/block; 8192 blocks.
__global__ __launch_bounds__(256) void dli_dot_kernel(
    const float* __restrict__ enc,    // [B*T, E]
    const int*   __restrict__ mask,   // [B*T]
    const float* __restrict__ fc_w,   // [H+E]
    float*       __restrict__ cterm)  // [B*T]
{
    const int t    = threadIdx.x;
    const int wid  = t >> 6;
    const int lane = t & 63;
    const int sub  = lane >> 5;
    const int li   = lane & 31;
    const long row = (long)blockIdx.x * 8 + wid * 2 + sub;

    if (mask[row] == 0) return;       // prefix mask: k >= len never read downstream

    const float4 w4 = *reinterpret_cast<const float4*>(fc_w + H + 4 * li);
    const float4 v  = *reinterpret_cast<const float4*>(enc + row * E + 4 * li);
    float p = v.x * w4.x + v.y * w4.y + v.z * w4.z + v.w * w4.w;
    #pragma unroll
    for (int off = 16; off >= 1; off >>= 1)
        p += __shfl_xor(p, off);
    if (li == 0) cterm[row] = p;
}

// ---------------- Phase 2: suffix-LSE per row + masked mean + finalize ----------------
__global__ __launch_bounds__(T) void dli_scan_kernel(
    const float* __restrict__ cterm,  // [B*T]
    const int*   __restrict__ mask,   // [B*T]
    double*      __restrict__ accum,  // ws[0]
    int*         __restrict__ scan_done,
    float*       __restrict__ out)
{
    const int b    = blockIdx.x;
    const int t    = threadIdx.x;
    const int lane = t & 63;
    const int wid  = t >> 6;

    __shared__ float s_c[T];
    __shared__ float s_a[T];
    __shared__ float s_b[T];
    __shared__ float s_red[8];
    __shared__ int   s_len;

    if (t == 0) s_len = 0;
    __syncthreads();

    const int mv = mask[b * T + t];
    unsigned long long bal = __ballot(mv != 0);
    if (lane == 0) atomicAdd(&s_len, __popcll(bal));

    s_c[t] = mv ? cterm[b * T + t] : 0.0f;   // masked entries unwritten (poison)
    __syncthreads();
    const int len = s_len;

    // row max over k in [3,len)
    float mval = (t >= 3 && t < len) ? s_c[t] : -INFINITY;
    #pragma unroll
    for (int off = 32; off >= 1; off >>= 1)
        mval = fmaxf(mval, __shfl_xor(mval, off));
    if (lane == 0) s_red[wid] = mval;
    __syncthreads();
    if (t == 0) {
        float m = s_red[0];
        #pragma unroll
        for (int i = 1; i < 8; i++) m = fmaxf(m, s_red[i]);
        s_red[0] = m;
    }
    __syncthreads();
    const float Mrow = s_red[0];

    // exp terms, then suffix inclusive sum (ping-pong Hillis-Steele, 9 steps)
    s_a[t] = (t >= 3 && t < len) ? expf(s_c[t] - Mrow) : 0.0f;
    __syncthreads();
    float* cur = s_a;
    float* nxt = s_b;
    #pragma unroll
    for (int d = 1; d < T; d <<= 1) {
        nxt[t] = cur[t] + ((t + d < T) ? cur[t + d] : 0.0f);
        float* tmp = cur; cur = nxt; nxt = tmp;
        __syncthreads();
    }

    float term = 0.0f;
    if (t >= 3 && t < len)
        term = Mrow + logf(cur[t]) - s_c[t];
    #pragma unroll
    for (int off = 32; off >= 1; off >>= 1)
        term += __shfl_xor(term, off);
    if (lane == 0) s_red[wid] = term;
    __syncthreads();

    if (t == 0) {
        float rs = 0.0f;
        #pragma unroll
        for (int i = 0; i < 8; i++) rs += s_red[i];
        int cnt = len - 3; if (cnt < 0) cnt = 0;
        atomicAdd(&accum[0], (double)rs);
        atomicAdd(&accum[1], (double)cnt);
        __threadfence();                       // order accum adds before arrival
        int old = atomicAdd(scan_done, 1);
        if (old == BSZ - 1) {                  // last block finalizes
            __threadfence();                   // acquire others' accum adds
            double a0 = atomicAdd(&accum[0], 0.0);
            double a1 = atomicAdd(&accum[1], 0.0);
            out[0] = (float)(a0 / a1);
        }
    }
}

extern "C" void kernel_launch(void* const* d_in, const int* in_sizes, int n_in,
                              void* d_out, int out_size, void* d_ws, size_t ws_size,
                              hipStream_t stream) {
    const float* enc  = (const float*)d_in[0];   // encoder_output [128,512,128] f32
    const int*   mask = (const int*)d_in[1];     // mask [128,512] i32
    const float* fc_w = (const float*)d_in[6];   // fc_w [1,256] f32
    // d_in[2..5] (LSTM weights) and d_in[7] (fc_b) cancel analytically.

    double* accum     = (double*)d_ws;
    int*    scan_done = (int*)((char*)d_ws + 16);
    float*  cterm     = (float*)((char*)d_ws + 1024);

    hipMemsetAsync(d_ws, 0, 32, stream);         // accum + scan_done

    dli_dot_kernel<<<(BSZ * T) / 8, 256, 0, stream>>>(enc, mask, fc_w, cterm);
    dli_scan_kernel<<<BSZ, T, 0, stream>>>(cterm, mask, accum, scan_done,
                                           (float*)d_out);
}